// Round 22
// baseline (84.611 us; speedup 1.0000x reference)
//
#include <hip/hip_runtime.h>
#include <math.h>

#define K 128
#define V 50257
#define H 128
#define B 256
#define T 1024
#define NSB 786   // score blocks = ceil(V/64)
#define WUP 4     // warmup steps (Delta*tau^3 ~ 2.4e-4, x128 chunks ~ 0.03 log-err)
#define CL 8      // counted steps per chunk
#define NCH 128   // chunks per chain
#define NST (CL + WUP)

typedef _Float16 half8 __attribute__((ext_vector_type(8)));
typedef float f32x4 __attribute__((ext_vector_type(4)));
typedef __fp16 fp16x2 __attribute__((ext_vector_type(2)));

__device__ __forceinline__ unsigned pkh2(float x, float y) {
  fp16x2 v = __builtin_amdgcn_cvt_pkrtz(x, y);
  return __builtin_bit_cast(unsigned, v);
}
__device__ __forceinline__ unsigned short f16b(float x) {
  fp16x2 v = __builtin_amdgcn_cvt_pkrtz(x, x);
  return (unsigned short)(__builtin_bit_cast(unsigned, v) & 0xFFFFu);
}

// DPP wave reduces (result valid in lane 63)
__device__ __forceinline__ float wave_max63(float x) {
  int xi;
#define MSTEP(ctrl, rm, bm)                                                          \
  xi = __builtin_amdgcn_update_dpp(__float_as_int(x), __float_as_int(x), ctrl, rm,   \
                                   bm, false);                                       \
  x = fmaxf(x, __int_as_float(xi));
  MSTEP(0x111, 0xf, 0xf)
  MSTEP(0x112, 0xf, 0xf)
  MSTEP(0x114, 0xf, 0xe)
  MSTEP(0x118, 0xf, 0xc)
  MSTEP(0x142, 0xa, 0xf)
  MSTEP(0x143, 0xc, 0xf)
#undef MSTEP
  return x;
}
__device__ __forceinline__ float wave_sum63(float x) {
  int xi;
#define SSTEP(ctrl, rm, bm)                                                          \
  xi = __builtin_amdgcn_update_dpp(0, __float_as_int(x), ctrl, rm, bm, true);        \
  x = x + __int_as_float(xi);
  SSTEP(0x111, 0xf, 0xf)
  SSTEP(0x112, 0xf, 0xf)
  SSTEP(0x114, 0xf, 0xe)
  SSTEP(0x118, 0xf, 0xc)
  SSTEP(0x142, 0xa, 0xf)
  SSTEP(0x143, 0xc, 0xf)
#undef SSTEP
  return x;
}

// fused prep: blocks 0..127 = transA row; block 128 = tagh + pi + zero(out)
__global__ void __launch_bounds__(128) k_prep(
    const float* __restrict__ trans_w, const float* __restrict__ trans_b,
    const float* __restrict__ trans_q, const float* __restrict__ tag_w,
    const float* __restrict__ initl, unsigned short* __restrict__ AbfH,
    uint4* __restrict__ Tbf, float* __restrict__ pivec, float* __restrict__ out) {
  __shared__ __align__(16) float qs[H];
  __shared__ float red[2];
  int bid = blockIdx.x;
  int j = threadIdx.x;
  if (bid < 128) {
    int i = bid;
    qs[j] = trans_q[j];
    __syncthreads();
    const float* wrow = trans_w + (size_t)(i * K + j) * H;
    float acc = 0.f;
#pragma unroll
    for (int h = 0; h < H; h += 4) {
      float4 w4 = *(const float4*)(wrow + h);
      float4 q4 = *(const float4*)(qs + h);
      acc += w4.x * q4.x + w4.y * q4.y + w4.z * q4.z + w4.w * q4.w;
    }
    float logit = acc + trans_b[i * K + j];
    int wid = j >> 6;
    float m = logit;
    for (int o = 32; o; o >>= 1) m = fmaxf(m, __shfl_xor(m, o, 64));
    if ((j & 63) == 0) red[wid] = m;
    __syncthreads();
    m = fmaxf(red[0], red[1]);
    __syncthreads();
    float e = __expf(logit - m);
    float s = e;
    for (int o = 32; o; o >>= 1) s += __shfl_xor(s, o, 64);
    if ((j & 63) == 0) red[wid] = s;
    __syncthreads();
    s = red[0] + red[1];
    float a = e / s;
    int kt = i >> 5;
    int g = (i & 31) >> 3;
    int lane = 16 * g + (j & 15);
    int n = j >> 4;
    int ee = i & 7;
    AbfH[(size_t)(((kt * 8 + n) * 64 + lane) * 8 + ee)] = f16b(a);
  } else {
    if (j == 0) out[0] = 0.f;
    // tagh: tag B-fragments
    for (int f = j; f < 2048; f += 128) {
      int lane = f & 63;
      int rest = f >> 6;
      int n = rest & 7, kt = rest >> 3;
      int k = 16 * n + (lane & 15);
      int d0 = 32 * kt + 8 * (lane >> 4);
      const float* src = tag_w + (size_t)k * K + d0;
      float4 a = *(const float4*)src;
      float4 c = *(const float4*)(src + 4);
      Tbf[f] = make_uint4(pkh2(a.x, a.y), pkh2(a.z, a.w), pkh2(c.x, c.y), pkh2(c.z, c.w));
    }
    // pi
    float v = initl[j];
    int wid = j >> 6;
    float m = v;
    for (int o = 32; o; o >>= 1) m = fmaxf(m, __shfl_xor(m, o, 64));
    if ((j & 63) == 0) red[wid] = m;
    __syncthreads();
    m = fmaxf(red[0], red[1]);
    __syncthreads();
    float e = __expf(v - m);
    float s = e;
    for (int o = 32; o; o >>= 1) s += __shfl_xor(s, o, 64);
    if ((j & 63) == 0) red[wid] = s;
    __syncthreads();
    s = red[0] + red[1];
    pivec[j] = e / s;
  }
}

// scoresH = tag.word^T + bias via MFMA, 64 words/block; + fused per-k lse partials
__global__ void __launch_bounds__(256) k_scores(const float* __restrict__ word_w,
                                                const float* __restrict__ word_b,
                                                const uint4* __restrict__ Tbf,
                                                _Float16* __restrict__ scoresH,
                                                float* __restrict__ pmaxP,
                                                float* __restrict__ psumP) {
  __shared__ __align__(16) uint4 TbfL[2048];        // 32 KB
  __shared__ __align__(16) _Float16 outT[64][136];  // 17.4 KB
  int tid = threadIdx.x;
  int wv = tid >> 6, l = tid & 63;
  int c = l & 15, g = l >> 4;
  int wbase = blockIdx.x * 64;
#pragma unroll
  for (int q = 0; q < 8; q++) TbfL[q * 256 + tid] = Tbf[q * 256 + tid];
  int wa = min(wbase + wv * 16 + c, V - 1);
  const float* wrow = word_w + (size_t)wa * K + 8 * g;
  uint4 A0, A1, A2, A3;
#define LDA(kt, dst)                                                        \
  {                                                                         \
    float4 x = *(const float4*)(wrow + 32 * kt);                            \
    float4 y = *(const float4*)(wrow + 32 * kt + 4);                        \
    dst = make_uint4(pkh2(x.x, x.y), pkh2(x.z, x.w), pkh2(y.x, y.y), pkh2(y.z, y.w)); \
  }
  LDA(0, A0) LDA(1, A1) LDA(2, A2) LDA(3, A3)
#undef LDA
  float wb[4];
#pragma unroll
  for (int r = 0; r < 4; r++) wb[r] = word_b[min(wbase + wv * 16 + 4 * g + r, V - 1)];
  __syncthreads();
  f32x4 acc[8];
#pragma unroll
  for (int n = 0; n < 8; n++) acc[n] = (f32x4){0.f, 0.f, 0.f, 0.f};
#define MK(kt, AV)                                                          \
  {                                                                         \
    half8 ao = __builtin_bit_cast(half8, AV);                               \
    _Pragma("unroll") for (int n = 0; n < 8; n++) {                         \
      half8 bo = __builtin_bit_cast(half8, TbfL[(kt * 8 + n) * 64 + l]);    \
      acc[n] = __builtin_amdgcn_mfma_f32_16x16x32_f16(ao, bo, acc[n], 0, 0, 0); \
    }                                                                       \
  }
  MK(0, A0) MK(1, A1) MK(2, A2) MK(3, A3)
#undef MK
#pragma unroll
  for (int n = 0; n < 8; n++) {
#pragma unroll
    for (int r = 0; r < 4; r++)
      outT[wv * 16 + 4 * g + r][16 * n + c] = (_Float16)(acc[n][r] + wb[r]);
  }
  __syncthreads();
#pragma unroll
  for (int q = 0; q < 4; q++) {
    int idx = q * 256 + tid;
    int wl = idx >> 4, part = idx & 15;
    int w = wbase + wl;
    if (w < V) {
      uint4 v = *(const uint4*)&outT[wl][part * 8];
      *(uint4*)&scoresH[(size_t)w * K + part * 8] = v;
    }
  }
  // fused per-k (max, sumexp) partials over this block's valid words
  int nw = min(64, V - wbase);
  int kk = tid & 127, hf = tid >> 7;
  float pm = -1e30f, psv = 0.f;
  for (int q = 0; q < 32; q++) {
    int wl = hf * 32 + q;
    if (wl < nw) {
      float v = (float)outT[wl][kk];
      if (v > pm) { psv *= __expf(pm - v); pm = v; }
      psv += __expf(v - pm);
    }
  }
  pmaxP[blockIdx.x * 256 + tid] = pm;
  psumP[blockIdx.x * 256 + tid] = psv;
}

// parallel lse: one block per state k; 256 threads reduce 786x2 partials
__global__ void __launch_bounds__(256) k_lsefin(const float* __restrict__ pmaxP,
                                                const float* __restrict__ psumP,
                                                float* __restrict__ lse) {
  __shared__ float sm[4], ss[4];
  int k = blockIdx.x;
  int tid = threadIdx.x;
  float m = -1e30f, s = 0.f;
  for (int e = tid; e < 2 * NSB; e += 256) {
    int blk = e >> 1, half = e & 1;
    float pm = pmaxP[blk * 256 + half * 128 + k];
    float pv = psumP[blk * 256 + half * 128 + k];
    float M = fmaxf(m, pm);
    s = s * __expf(m - M) + pv * __expf(pm - M);
    m = M;
  }
#pragma unroll
  for (int o = 32; o; o >>= 1) {
    float mo = __shfl_xor(m, o, 64);
    float so = __shfl_xor(s, o, 64);
    float M = fmaxf(m, mo);
    s = s * __expf(m - M) + so * __expf(mo - M);
    m = M;
  }
  int wv = tid >> 6;
  if ((tid & 63) == 0) { sm[wv] = m; ss[wv] = s; }
  __syncthreads();
  if (tid == 0) {
    float M = fmaxf(fmaxf(sm[0], sm[1]), fmaxf(sm[2], sm[3]));
    float st = ss[0] * __expf(sm[0] - M) + ss[1] * __expf(sm[1] - M) +
               ss[2] * __expf(sm[2] - M) + ss[3] * __expf(sm[3] - M);
    lse[k] = M + __logf(st);
  }
}

// fused: mB[w] = max_k(score-lse), then in-place scoresH -> exp(score-lse-mB) (f16)
__global__ void __launch_bounds__(256) k_expbm(_Float16* __restrict__ scoresH,
                                               const float* __restrict__ lse,
                                               float* __restrict__ mB) {
  __shared__ __align__(16) float ls[K];
  int tid = threadIdx.x;
  if (tid < K) ls[tid] = lse[tid];
  __syncthreads();
  int w = blockIdx.x * 256 + tid;
  if (w >= V) return;
  uint4* rowv = (uint4*)(scoresH + (size_t)w * K);
  float mx = -1e30f;
#pragma unroll
  for (int c = 0; c < 16; c++) {
    uint4 u = rowv[c];
    const _Float16* hp = (const _Float16*)&u;
#pragma unroll
    for (int d = 0; d < 8; d++) mx = fmaxf(mx, (float)hp[d] - ls[8 * c + d]);
  }
  mB[w] = mx;
#pragma unroll
  for (int c = 0; c < 16; c++) {
    uint4 u = rowv[c];
    const _Float16* hp = (const _Float16*)&u;
    float e[8];
#pragma unroll
    for (int d = 0; d < 8; d++) e[d] = __expf((float)hp[d] - ls[8 * c + d] - mx);
    uint4 o;
    o.x = pkh2(e[0], e[1]); o.y = pkh2(e[2], e[3]);
    o.z = pkh2(e[4], e[5]); o.w = pkh2(e[6], e[7]);
    rowv[c] = o;
  }
}

// chunk-parallel forward: 8 waves, 128 chunks of CL=8 counted steps (WUP=4 warmup);
// builtin MFMA (B from LDS), Qt-transposed LDS exchange, f16 eb table; atomic loss.
__global__ void __launch_bounds__(512, 1) k_forward(
    const int* __restrict__ emis, const _Float16* __restrict__ expbH,
    const float* __restrict__ mB, const uint4* __restrict__ Abf_g,
    const float* __restrict__ pivec, float* __restrict__ out) {
  __shared__ __align__(16) uint4 AbfL[2048];  // 32 KB
  __shared__ float Qt[8][16 * 132];           // 67.6 KB, per-wave [m][j] w/ pad
  __shared__ int es[T];
  __shared__ float red[8];
  int b = blockIdx.x;
  int tid = threadIdx.x;
  int wv = tid >> 6, l = tid & 63;
  int c16 = l & 15, g = l >> 4;
  int chunk = 16 * wv + c16;   // 0..127
  for (int i = tid; i < T; i += 512) es[i] = emis[b * T + i];
  for (int p = tid; p < 2048; p += 512) AbfL[p] = Abf_g[p];
  int Jb[4];
#pragma unroll
  for (int kt = 0; kt < 4; kt++) Jb[kt] = 32 * kt + 8 * g;
  __syncthreads();
  // exact alpha(t=0)
  int w0 = es[0];
  float mb0 = mB[w0];
  float a0v = pivec[2 * l] * (float)expbH[(size_t)w0 * K + 2 * l];
  float a1v = pivec[2 * l + 1] * (float)expbH[(size_t)w0 * K + 2 * l + 1];
  float am = wave_max63(fmaxf(a0v, a1v));
  float mu1 = __int_as_float(__builtin_amdgcn_readlane(__float_as_int(am), 63));
  mu1 = fmaxf(mu1, 1e-30f);
  float lmu1 = __logf(mu1);
  uint4 P0[4];
  {
    float inv = 1.0f / mu1;
#pragma unroll
    for (int kt = 0; kt < 4; kt++) {
      float v[8];
#pragma unroll
      for (int i = 0; i < 8; i++) {
        int j = Jb[kt] + i;
        v[i] = pivec[j] * (float)expbH[(size_t)w0 * K + j] * inv;
      }
      P0[kt] = make_uint4(pkh2(v[0], v[1]), pkh2(v[2], v[3]), pkh2(v[4], v[5]), pkh2(v[6], v[7]));
    }
  }
  uint4 Pk[4];
  unsigned one2 = 0x3C003C00u;
  Pk[0] = Pk[1] = Pk[2] = Pk[3] = make_uint4(one2, one2, one2, one2);
  float zprev = 1.0f, lzS = 0.f, lzE = 0.f, logS = 0.f, Cacc = 0.f;
  int cend = (chunk == NCH - 1) ? (WUP + CL - 2) : (WUP + CL - 1);
  float* Qw = Qt[wv];
  int t0 = max(CL * chunk - (WUP - 1), 0);
  int tok0 = es[t0];
  float mbC = mB[tok0];
  uint4 ebC[4];
  {
    const uint4* ebp = (const uint4*)(expbH + (size_t)tok0 * K);
#pragma unroll
    for (int kt = 0; kt < 4; kt++) ebC[kt] = ebp[4 * kt + g];
  }
  for (int s = 0; s < NST; s++) {
    int tn = CL * chunk + (s + 1) - (WUP - 1);
    tn = max(tn, 0); tn = min(tn, T - 1);
    int tokN = es[tn];
    float mbN = mB[tokN];
    const uint4* ebpN = (const uint4*)(expbH + (size_t)tokN * K);
    uint4 ebN[4];
#pragma unroll
    for (int kt = 0; kt < 4; kt++) ebN[kt] = ebpN[4 * kt + g];
    // 32 mfma: acc[n] = sum_kt P[kt] * Abf[kt][n]
    f32x4 acc[8];
#pragma unroll
    for (int n = 0; n < 8; n++) acc[n] = (f32x4){0.f, 0.f, 0.f, 0.f};
#pragma unroll
    for (int kt = 0; kt < 4; kt++) {
      half8 ao = __builtin_bit_cast(half8, Pk[kt]);
#pragma unroll
      for (int n = 0; n < 8; n++) {
        half8 bo = __builtin_bit_cast(half8, AbfL[(kt * 8 + n) * 64 + l]);
        acc[n] = __builtin_amdgcn_mfma_f32_16x16x32_f16(ao, bo, acc[n], 0, 0, 0);
      }
    }
    // scatter D to Qt[m=4g+r][j=16n+c16]  (2-way banks: free)
#pragma unroll
    for (int n = 0; n < 8; n++) {
#pragma unroll
      for (int r = 0; r < 4; r++) Qw[(4 * g + r) * 132 + 16 * n + c16] = acc[n][r];
    }
    asm volatile("s_waitcnt lgkmcnt(0)" ::: "memory");
    __builtin_amdgcn_sched_barrier(0);
    // gather own chunk (row m=c16): p = q * eb * rr
    float rr = __builtin_amdgcn_rcpf(fmaxf(zprev, 1e-30f));
    float lzp = __logf(fmaxf(zprev, 1e-30f));
    float pmax = 0.f, lsum = 0.f;
    uint4 newP[4];
#pragma unroll
    for (int kt = 0; kt < 4; kt++) {
      f32x4 q0 = *(const f32x4*)&Qw[c16 * 132 + Jb[kt]];
      f32x4 q1 = *(const f32x4*)&Qw[c16 * 132 + Jb[kt] + 4];
      const _Float16* ebh = (const _Float16*)&ebC[kt];
      float pv[8];
#pragma unroll
      for (int i = 0; i < 4; i++) {
        float p = q0[i] * (float)ebh[i] * rr;
        pv[i] = p; pmax = fmaxf(pmax, p); lsum += p;
      }
#pragma unroll
      for (int i = 0; i < 4; i++) {
        float p = q1[i] * (float)ebh[4 + i] * rr;
        pv[4 + i] = p; pmax = fmaxf(pmax, p); lsum += p;
      }
      newP[kt] = make_uint4(pkh2(pv[0], pv[1]), pkh2(pv[2], pv[3]),
                            pkh2(pv[4], pv[5]), pkh2(pv[6], pv[7]));
    }
    pmax = fmaxf(pmax, __shfl_xor(pmax, 16, 64));
    pmax = fmaxf(pmax, __shfl_xor(pmax, 32, 64));
    float znew = pmax;
    if (s == WUP - 1) {
      if (chunk == 0) {
#pragma unroll
        for (int kt = 0; kt < 4; kt++) newP[kt] = P0[kt];
        znew = 1.0f;
      }
      lzS = __logf(fmaxf(znew, 1e-30f));
    }
    bool counted = (s >= WUP) && (s <= cend);
    if (counted) Cacc += lzp + mbC;
    if (s == WUP + CL - 2) {
      float ssum = lsum + __shfl_xor(lsum, 16, 64);
      ssum += __shfl_xor(ssum, 32, 64);
      logS = __logf(fmaxf(ssum, 1e-30f));
    }
    if (s == WUP + CL - 1) lzE = __logf(fmaxf(znew, 1e-30f));
#pragma unroll
    for (int kt = 0; kt < 4; kt++) Pk[kt] = newP[kt];
    zprev = znew;
#pragma unroll
    for (int kt = 0; kt < 4; kt++) ebC[kt] = ebN[kt];
    mbC = mbN;
  }
  // epilogue: per-chunk R -> block sum -> atomic loss
  float Rv = Cacc - lzS;
  Rv += (chunk == NCH - 1) ? logS : lzE;
  if (chunk == 0) Rv += mb0 + lmu1;
  float val = (l < 16) ? Rv : 0.f;
  float ws = wave_sum63(val);
  if (l == 63) red[wv] = ws;
  __syncthreads();
  if (tid == 0) {
    float tot = red[0] + red[1] + red[2] + red[3] + red[4] + red[5] + red[6] + red[7];
    atomicAdd(out, -tot * (1.0f / (float)B));
  }
}

extern "C" void kernel_launch(void* const* d_in, const int* in_sizes, int n_in,
                              void* d_out, int out_size, void* d_ws, size_t ws_size,
                              hipStream_t stream) {
  const int*   emis   = (const int*)d_in[0];
  const float* initl  = (const float*)d_in[1];
  const float* tagw   = (const float*)d_in[2];
  const float* wordw  = (const float*)d_in[3];
  const float* wordb  = (const float*)d_in[4];
  const float* transw = (const float*)d_in[5];
  const float* transb = (const float*)d_in[6];
  const float* transq = (const float*)d_in[7];
  float* ws = (float*)d_ws;
  size_t off = 0;
  _Float16* scoresH = (_Float16*)(ws + off); off += (size_t)V * K / 2;  // scores -> eb in place
  uint4* Abf_g      = (uint4*)(ws + off);    off += 8192;
  uint4* Tbf_g      = (uint4*)(ws + off);    off += 8192;
  float* pivec      = ws + off; off += K;
  float* lse        = ws + off; off += K;
  float* pmaxP      = ws + off; off += (size_t)NSB * 256;
  float* psumP      = ws + off; off += (size_t)NSB * 256;
  float* mB         = ws + off; off += (size_t)V + 64;
  float* out = (float*)d_out;

  hipLaunchKernelGGL(k_prep, dim3(129), dim3(128), 0, stream,
                     transw, transb, transq, tagw, initl,
                     (unsigned short*)Abf_g, Tbf_g, pivec, out);
  hipLaunchKernelGGL(k_scores, dim3(NSB), dim3(256), 0, stream,
                     wordw, wordb, Tbf_g, scoresH, pmaxP, psumP);
  hipLaunchKernelGGL(k_lsefin, dim3(K), dim3(256), 0, stream, pmaxP, psumP, lse);
  hipLaunchKernelGGL(k_expbm, dim3((V + 255) / 256), dim3(256), 0, stream, scoresH, lse, mB);
  hipLaunchKernelGGL(k_forward, dim3(B), dim3(512), 0, stream, emis, scoresH, mB, Abf_g, pivec, out);
}

// Round 23
// 67.907 us; speedup vs baseline: 1.2460x; 1.2460x over previous
//
#include <hip/hip_runtime.h>
#include <math.h>

#define K 128
#define V 50257
#define H 128
#define B 256
#define T 1024
#define NSB 786   // score blocks = ceil(V/64)
#define WUP 4     // warmup steps (validated by R22: absmax 0.0)
#define CL 8      // counted steps per chunk
#define NCH 128   // chunks per chain
#define NST (CL + WUP)

typedef _Float16 half8 __attribute__((ext_vector_type(8)));
typedef float f32x4 __attribute__((ext_vector_type(4)));
typedef __fp16 fp16x2 __attribute__((ext_vector_type(2)));

__device__ __forceinline__ unsigned pkh2(float x, float y) {
  fp16x2 v = __builtin_amdgcn_cvt_pkrtz(x, y);
  return __builtin_bit_cast(unsigned, v);
}
__device__ __forceinline__ unsigned short f16b(float x) {
  fp16x2 v = __builtin_amdgcn_cvt_pkrtz(x, x);
  return (unsigned short)(__builtin_bit_cast(unsigned, v) & 0xFFFFu);
}

// DPP wave reduces (result valid in lane 63)
__device__ __forceinline__ float wave_max63(float x) {
  int xi;
#define MSTEP(ctrl, rm, bm)                                                          \
  xi = __builtin_amdgcn_update_dpp(__float_as_int(x), __float_as_int(x), ctrl, rm,   \
                                   bm, false);                                       \
  x = fmaxf(x, __int_as_float(xi));
  MSTEP(0x111, 0xf, 0xf)
  MSTEP(0x112, 0xf, 0xf)
  MSTEP(0x114, 0xf, 0xe)
  MSTEP(0x118, 0xf, 0xc)
  MSTEP(0x142, 0xa, 0xf)
  MSTEP(0x143, 0xc, 0xf)
#undef MSTEP
  return x;
}
__device__ __forceinline__ float wave_sum63(float x) {
  int xi;
#define SSTEP(ctrl, rm, bm)                                                          \
  xi = __builtin_amdgcn_update_dpp(0, __float_as_int(x), ctrl, rm, bm, true);        \
  x = x + __int_as_float(xi);
  SSTEP(0x111, 0xf, 0xf)
  SSTEP(0x112, 0xf, 0xf)
  SSTEP(0x114, 0xf, 0xe)
  SSTEP(0x118, 0xf, 0xc)
  SSTEP(0x142, 0xa, 0xf)
  SSTEP(0x143, 0xc, 0xf)
#undef SSTEP
  return x;
}

// fused prep: blocks 0..127 = transA row; block 128 = tagh + pi + zero(out)
__global__ void __launch_bounds__(128) k_prep(
    const float* __restrict__ trans_w, const float* __restrict__ trans_b,
    const float* __restrict__ trans_q, const float* __restrict__ tag_w,
    const float* __restrict__ initl, unsigned short* __restrict__ AbfH,
    uint4* __restrict__ Tbf, float* __restrict__ pivec, float* __restrict__ out) {
  __shared__ __align__(16) float qs[H];
  __shared__ float red[2];
  int bid = blockIdx.x;
  int j = threadIdx.x;
  if (bid < 128) {
    int i = bid;
    qs[j] = trans_q[j];
    __syncthreads();
    const float* wrow = trans_w + (size_t)(i * K + j) * H;
    float acc = 0.f;
#pragma unroll
    for (int h = 0; h < H; h += 4) {
      float4 w4 = *(const float4*)(wrow + h);
      float4 q4 = *(const float4*)(qs + h);
      acc += w4.x * q4.x + w4.y * q4.y + w4.z * q4.z + w4.w * q4.w;
    }
    float logit = acc + trans_b[i * K + j];
    int wid = j >> 6;
    float m = logit;
    for (int o = 32; o; o >>= 1) m = fmaxf(m, __shfl_xor(m, o, 64));
    if ((j & 63) == 0) red[wid] = m;
    __syncthreads();
    m = fmaxf(red[0], red[1]);
    __syncthreads();
    float e = __expf(logit - m);
    float s = e;
    for (int o = 32; o; o >>= 1) s += __shfl_xor(s, o, 64);
    if ((j & 63) == 0) red[wid] = s;
    __syncthreads();
    s = red[0] + red[1];
    float a = e / s;
    int kt = i >> 5;
    int g = (i & 31) >> 3;
    int lane = 16 * g + (j & 15);
    int n = j >> 4;
    int ee = i & 7;
    AbfH[(size_t)(((kt * 8 + n) * 64 + lane) * 8 + ee)] = f16b(a);
  } else {
    if (j == 0) out[0] = 0.f;
    // tagh: tag B-fragments
    for (int f = j; f < 2048; f += 128) {
      int lane = f & 63;
      int rest = f >> 6;
      int n = rest & 7, kt = rest >> 3;
      int k = 16 * n + (lane & 15);
      int d0 = 32 * kt + 8 * (lane >> 4);
      const float* src = tag_w + (size_t)k * K + d0;
      float4 a = *(const float4*)src;
      float4 c = *(const float4*)(src + 4);
      Tbf[f] = make_uint4(pkh2(a.x, a.y), pkh2(a.z, a.w), pkh2(c.x, c.y), pkh2(c.z, c.w));
    }
    // pi
    float v = initl[j];
    int wid = j >> 6;
    float m = v;
    for (int o = 32; o; o >>= 1) m = fmaxf(m, __shfl_xor(m, o, 64));
    if ((j & 63) == 0) red[wid] = m;
    __syncthreads();
    m = fmaxf(red[0], red[1]);
    __syncthreads();
    float e = __expf(v - m);
    float s = e;
    for (int o = 32; o; o >>= 1) s += __shfl_xor(s, o, 64);
    if ((j & 63) == 0) red[wid] = s;
    __syncthreads();
    s = red[0] + red[1];
    pivec[j] = e / s;
  }
}

// scoresH = tag.word^T + bias via MFMA, 64 words/block; + fused per-k lse partials
__global__ void __launch_bounds__(256) k_scores(const float* __restrict__ word_w,
                                                const float* __restrict__ word_b,
                                                const uint4* __restrict__ Tbf,
                                                _Float16* __restrict__ scoresH,
                                                float* __restrict__ pmaxP,
                                                float* __restrict__ psumP) {
  __shared__ __align__(16) uint4 TbfL[2048];        // 32 KB
  __shared__ __align__(16) _Float16 outT[64][136];  // 17.4 KB
  int tid = threadIdx.x;
  int wv = tid >> 6, l = tid & 63;
  int c = l & 15, g = l >> 4;
  int wbase = blockIdx.x * 64;
#pragma unroll
  for (int q = 0; q < 8; q++) TbfL[q * 256 + tid] = Tbf[q * 256 + tid];
  int wa = min(wbase + wv * 16 + c, V - 1);
  const float* wrow = word_w + (size_t)wa * K + 8 * g;
  uint4 A0, A1, A2, A3;
#define LDA(kt, dst)                                                        \
  {                                                                         \
    float4 x = *(const float4*)(wrow + 32 * kt);                            \
    float4 y = *(const float4*)(wrow + 32 * kt + 4);                        \
    dst = make_uint4(pkh2(x.x, x.y), pkh2(x.z, x.w), pkh2(y.x, y.y), pkh2(y.z, y.w)); \
  }
  LDA(0, A0) LDA(1, A1) LDA(2, A2) LDA(3, A3)
#undef LDA
  float wb[4];
#pragma unroll
  for (int r = 0; r < 4; r++) wb[r] = word_b[min(wbase + wv * 16 + 4 * g + r, V - 1)];
  __syncthreads();
  f32x4 acc[8];
#pragma unroll
  for (int n = 0; n < 8; n++) acc[n] = (f32x4){0.f, 0.f, 0.f, 0.f};
#define MK(kt, AV)                                                          \
  {                                                                         \
    half8 ao = __builtin_bit_cast(half8, AV);                               \
    _Pragma("unroll") for (int n = 0; n < 8; n++) {                         \
      half8 bo = __builtin_bit_cast(half8, TbfL[(kt * 8 + n) * 64 + l]);    \
      acc[n] = __builtin_amdgcn_mfma_f32_16x16x32_f16(ao, bo, acc[n], 0, 0, 0); \
    }                                                                       \
  }
  MK(0, A0) MK(1, A1) MK(2, A2) MK(3, A3)
#undef MK
#pragma unroll
  for (int n = 0; n < 8; n++) {
#pragma unroll
    for (int r = 0; r < 4; r++)
      outT[wv * 16 + 4 * g + r][16 * n + c] = (_Float16)(acc[n][r] + wb[r]);
  }
  __syncthreads();
#pragma unroll
  for (int q = 0; q < 4; q++) {
    int idx = q * 256 + tid;
    int wl = idx >> 4, part = idx & 15;
    int w = wbase + wl;
    if (w < V) {
      uint4 v = *(const uint4*)&outT[wl][part * 8];
      *(uint4*)&scoresH[(size_t)w * K + part * 8] = v;
    }
  }
  // fused per-k (max, sumexp) partials over this block's valid words
  int nw = min(64, V - wbase);
  int kk = tid & 127, hf = tid >> 7;
  float pm = -1e30f, psv = 0.f;
  for (int q = 0; q < 32; q++) {
    int wl = hf * 32 + q;
    if (wl < nw) {
      float v = (float)outT[wl][kk];
      if (v > pm) { psv *= __expf(pm - v); pm = v; }
      psv += __expf(v - pm);
    }
  }
  pmaxP[blockIdx.x * 256 + tid] = pm;
  psumP[blockIdx.x * 256 + tid] = psv;
}

// parallel lse: one block per state k; 256 threads reduce 786x2 partials
__global__ void __launch_bounds__(256) k_lsefin(const float* __restrict__ pmaxP,
                                                const float* __restrict__ psumP,
                                                float* __restrict__ lse) {
  __shared__ float sm[4], ss[4];
  int k = blockIdx.x;
  int tid = threadIdx.x;
  float m = -1e30f, s = 0.f;
  for (int e = tid; e < 2 * NSB; e += 256) {
    int blk = e >> 1, half = e & 1;
    float pm = pmaxP[blk * 256 + half * 128 + k];
    float pv = psumP[blk * 256 + half * 128 + k];
    float M = fmaxf(m, pm);
    s = s * __expf(m - M) + pv * __expf(pm - M);
    m = M;
  }
#pragma unroll
  for (int o = 32; o; o >>= 1) {
    float mo = __shfl_xor(m, o, 64);
    float so = __shfl_xor(s, o, 64);
    float M = fmaxf(m, mo);
    s = s * __expf(m - M) + so * __expf(mo - M);
    m = M;
  }
  int wv = tid >> 6;
  if ((tid & 63) == 0) { sm[wv] = m; ss[wv] = s; }
  __syncthreads();
  if (tid == 0) {
    float M = fmaxf(fmaxf(sm[0], sm[1]), fmaxf(sm[2], sm[3]));
    float st = ss[0] * __expf(sm[0] - M) + ss[1] * __expf(sm[1] - M) +
               ss[2] * __expf(sm[2] - M) + ss[3] * __expf(sm[3] - M);
    lse[k] = M + __logf(st);
  }
}

// read-only: mB[w] = max_k(score[w][k] - lse[k])   (scores stay RAW)
__global__ void __launch_bounds__(256) k_rowmax(const _Float16* __restrict__ scoresH,
                                                const float* __restrict__ lse,
                                                float* __restrict__ mB) {
  __shared__ __align__(16) float ls[K];
  int tid = threadIdx.x;
  if (tid < K) ls[tid] = lse[tid];
  __syncthreads();
  int w = blockIdx.x * 256 + tid;
  if (w >= V) return;
  const uint4* rowv = (const uint4*)(scoresH + (size_t)w * K);
  float mx = -1e30f;
#pragma unroll
  for (int c = 0; c < 16; c++) {
    uint4 u = rowv[c];
    const _Float16* hp = (const _Float16*)&u;
#pragma unroll
    for (int d = 0; d < 8; d++) mx = fmaxf(mx, (float)hp[d] - ls[8 * c + d]);
  }
  mB[w] = mx;
}

// chunk-parallel forward: 8 waves, 128 chunks of CL=8 counted steps (WUP=4 warmup);
// builtin MFMA (B from LDS), Qt-transposed LDS exchange; on-the-fly f32 emission
// exp; atomic loss epilogue. No block sync in the T-loop.
__global__ void __launch_bounds__(512, 1) k_forward(
    const int* __restrict__ emis, const _Float16* __restrict__ scoresH,
    const float* __restrict__ lse, const float* __restrict__ mB,
    const uint4* __restrict__ Abf_g, const float* __restrict__ pivec,
    float* __restrict__ out) {
  __shared__ __align__(16) uint4 AbfL[2048];  // 32 KB
  __shared__ float Qt[8][16 * 132];           // 67.6 KB, per-wave [m][j] w/ pad
  __shared__ int es[T];
  __shared__ float red[8];
  int b = blockIdx.x;
  int tid = threadIdx.x;
  int wv = tid >> 6, l = tid & 63;
  int c16 = l & 15, g = l >> 4;
  int chunk = 16 * wv + c16;   // 0..127
  for (int i = tid; i < T; i += 512) es[i] = emis[b * T + i];
  for (int p = tid; p < 2048; p += 512) AbfL[p] = Abf_g[p];
  int Jb[4];
#pragma unroll
  for (int kt = 0; kt < 4; kt++) Jb[kt] = 32 * kt + 8 * g;
  // per-lane lse registers
  f32x4 lseR[8];
#pragma unroll
  for (int kt = 0; kt < 4; kt++) {
    lseR[2 * kt] = *(const f32x4*)(lse + Jb[kt]);
    lseR[2 * kt + 1] = *(const f32x4*)(lse + Jb[kt] + 4);
  }
  float2 lse2 = *(const float2*)(lse + 2 * l);
  __syncthreads();
  // exact alpha(t=0)
  int w0 = es[0];
  float mb0 = mB[w0];
  float2 sc2;
  {
    const _Float16* s0p = scoresH + (size_t)w0 * K + 2 * l;
    sc2.x = (float)s0p[0]; sc2.y = (float)s0p[1];
  }
  float a0v = pivec[2 * l] * __expf(sc2.x - lse2.x - mb0);
  float a1v = pivec[2 * l + 1] * __expf(sc2.y - lse2.y - mb0);
  float am = wave_max63(fmaxf(a0v, a1v));
  float mu1 = __int_as_float(__builtin_amdgcn_readlane(__float_as_int(am), 63));
  mu1 = fmaxf(mu1, 1e-30f);
  float lmu1 = __logf(mu1);
  uint4 P0[4];
  {
    float inv = 1.0f / mu1;
    const uint4* s0v = (const uint4*)(scoresH + (size_t)w0 * K);
#pragma unroll
    for (int kt = 0; kt < 4; kt++) {
      uint4 su = s0v[4 * kt + g];
      const _Float16* sh = (const _Float16*)&su;
      float v[8];
#pragma unroll
      for (int i = 0; i < 4; i++)
        v[i] = pivec[Jb[kt] + i] * __expf((float)sh[i] - lseR[2 * kt][i] - mb0) * inv;
#pragma unroll
      for (int i = 0; i < 4; i++)
        v[4 + i] = pivec[Jb[kt] + 4 + i] * __expf((float)sh[4 + i] - lseR[2 * kt + 1][i] - mb0) * inv;
      P0[kt] = make_uint4(pkh2(v[0], v[1]), pkh2(v[2], v[3]), pkh2(v[4], v[5]), pkh2(v[6], v[7]));
    }
  }
  uint4 Pk[4];
  unsigned one2 = 0x3C003C00u;
  Pk[0] = Pk[1] = Pk[2] = Pk[3] = make_uint4(one2, one2, one2, one2);
  float zprev = 1.0f, lzS = 0.f, lzE = 0.f, logS = 0.f, Cacc = 0.f;
  int cend = (chunk == NCH - 1) ? (WUP + CL - 2) : (WUP + CL - 1);
  float* Qw = Qt[wv];
  int t0 = max(CL * chunk - (WUP - 1), 0);
  int tok0 = es[t0];
  float mbC = mB[tok0];
  uint4 sbC[4];   // raw score fragments for current step's token
  {
    const uint4* sp = (const uint4*)(scoresH + (size_t)tok0 * K);
#pragma unroll
    for (int kt = 0; kt < 4; kt++) sbC[kt] = sp[4 * kt + g];
  }
  for (int s = 0; s < NST; s++) {
    int tn = CL * chunk + (s + 1) - (WUP - 1);
    tn = max(tn, 0); tn = min(tn, T - 1);
    int tokN = es[tn];
    float mbN = mB[tokN];
    const uint4* spN = (const uint4*)(scoresH + (size_t)tokN * K);
    uint4 sbN[4];
#pragma unroll
    for (int kt = 0; kt < 4; kt++) sbN[kt] = spN[4 * kt + g];
    // 32 mfma: acc[n] = sum_kt P[kt] * Abf[kt][n]
    f32x4 acc[8];
#pragma unroll
    for (int n = 0; n < 8; n++) acc[n] = (f32x4){0.f, 0.f, 0.f, 0.f};
#pragma unroll
    for (int kt = 0; kt < 4; kt++) {
      half8 ao = __builtin_bit_cast(half8, Pk[kt]);
#pragma unroll
      for (int n = 0; n < 8; n++) {
        half8 bo = __builtin_bit_cast(half8, AbfL[(kt * 8 + n) * 64 + l]);
        acc[n] = __builtin_amdgcn_mfma_f32_16x16x32_f16(ao, bo, acc[n], 0, 0, 0);
      }
    }
    // scatter D to Qt[m=4g+r][j=16n+c16]  (2-way banks: free)
#pragma unroll
    for (int n = 0; n < 8; n++) {
#pragma unroll
      for (int r = 0; r < 4; r++) Qw[(4 * g + r) * 132 + 16 * n + c16] = acc[n][r];
    }
    asm volatile("s_waitcnt lgkmcnt(0)" ::: "memory");
    __builtin_amdgcn_sched_barrier(0);
    // gather own chunk (row m=c16): p = q * exp(s - lse - mb) * rr
    float rr = __builtin_amdgcn_rcpf(fmaxf(zprev, 1e-30f));
    float lzp = __logf(fmaxf(zprev, 1e-30f));
    float pmax = 0.f, lsum = 0.f;
    uint4 newP[4];
#pragma unroll
    for (int kt = 0; kt < 4; kt++) {
      f32x4 q0 = *(const f32x4*)&Qw[c16 * 132 + Jb[kt]];
      f32x4 q1 = *(const f32x4*)&Qw[c16 * 132 + Jb[kt] + 4];
      const _Float16* sh = (const _Float16*)&sbC[kt];
      float pv[8];
#pragma unroll
      for (int i = 0; i < 4; i++) {
        float eb = __expf((float)sh[i] - lseR[2 * kt][i] - mbC);
        float p = q0[i] * eb * rr;
        pv[i] = p; pmax = fmaxf(pmax, p); lsum += p;
      }
#pragma unroll
      for (int i = 0; i < 4; i++) {
        float eb = __expf((float)sh[4 + i] - lseR[2 * kt + 1][i] - mbC);
        float p = q1[i] * eb * rr;
        pv[4 + i] = p; pmax = fmaxf(pmax, p); lsum += p;
      }
      newP[kt] = make_uint4(pkh2(pv[0], pv[1]), pkh2(pv[2], pv[3]),
                            pkh2(pv[4], pv[5]), pkh2(pv[6], pv[7]));
    }
    pmax = fmaxf(pmax, __shfl_xor(pmax, 16, 64));
    pmax = fmaxf(pmax, __shfl_xor(pmax, 32, 64));
    float znew = pmax;
    if (s == WUP - 1) {
      if (chunk == 0) {
#pragma unroll
        for (int kt = 0; kt < 4; kt++) newP[kt] = P0[kt];
        znew = 1.0f;
      }
      lzS = __logf(fmaxf(znew, 1e-30f));
    }
    bool counted = (s >= WUP) && (s <= cend);
    if (counted) Cacc += lzp + mbC;
    if (s == WUP + CL - 2) {
      float ssum = lsum + __shfl_xor(lsum, 16, 64);
      ssum += __shfl_xor(ssum, 32, 64);
      logS = __logf(fmaxf(ssum, 1e-30f));
    }
    if (s == WUP + CL - 1) lzE = __logf(fmaxf(znew, 1e-30f));
#pragma unroll
    for (int kt = 0; kt < 4; kt++) Pk[kt] = newP[kt];
    zprev = znew;
#pragma unroll
    for (int kt = 0; kt < 4; kt++) sbC[kt] = sbN[kt];
    mbC = mbN;
  }
  // epilogue: per-chunk R -> block sum -> atomic loss
  float Rv = Cacc - lzS;
  Rv += (chunk == NCH - 1) ? logS : lzE;
  if (chunk == 0) Rv += mb0 + lmu1;
  float val = (l < 16) ? Rv : 0.f;
  float ws = wave_sum63(val);
  if (l == 63) red[wv] = ws;
  __syncthreads();
  if (tid == 0) {
    float tot = red[0] + red[1] + red[2] + red[3] + red[4] + red[5] + red[6] + red[7];
    atomicAdd(out, -tot * (1.0f / (float)B));
  }
}

extern "C" void kernel_launch(void* const* d_in, const int* in_sizes, int n_in,
                              void* d_out, int out_size, void* d_ws, size_t ws_size,
                              hipStream_t stream) {
  const int*   emis   = (const int*)d_in[0];
  const float* initl  = (const float*)d_in[1];
  const float* tagw   = (const float*)d_in[2];
  const float* wordw  = (const float*)d_in[3];
  const float* wordb  = (const float*)d_in[4];
  const float* transw = (const float*)d_in[5];
  const float* transb = (const float*)d_in[6];
  const float* transq = (const float*)d_in[7];
  float* ws = (float*)d_ws;
  size_t off = 0;
  _Float16* scoresH = (_Float16*)(ws + off); off += (size_t)V * K / 2;
  uint4* Abf_g      = (uint4*)(ws + off);    off += 8192;
  uint4* Tbf_g      = (uint4*)(ws + off);    off += 8192;
  float* pivec      = ws + off; off += K;
  float* lse        = ws + off; off += K;
  float* pmaxP      = ws + off; off += (size_t)NSB * 256;
  float* psumP      = ws + off; off += (size_t)NSB * 256;
  float* mB         = ws + off; off += (size_t)V + 64;
  float* out = (float*)d_out;

  hipLaunchKernelGGL(k_prep, dim3(129), dim3(128), 0, stream,
                     transw, transb, transq, tagw, initl,
                     (unsigned short*)Abf_g, Tbf_g, pivec, out);
  hipLaunchKernelGGL(k_scores, dim3(NSB), dim3(256), 0, stream,
                     wordw, wordb, Tbf_g, scoresH, pmaxP, psumP);
  hipLaunchKernelGGL(k_lsefin, dim3(K), dim3(256), 0, stream, pmaxP, psumP, lse);
  hipLaunchKernelGGL(k_rowmax, dim3((V + 255) / 256), dim3(256), 0, stream, scoresH, lse, mB);
  hipLaunchKernelGGL(k_forward, dim3(B), dim3(512), 0, stream, emis, scoresH, lse, mB, Abf_g, pivec, out);
}

// Round 24
// 66.823 us; speedup vs baseline: 1.2662x; 1.0162x over previous
//
#include <hip/hip_runtime.h>
#include <math.h>

#define K 128
#define V 50257
#define H 128
#define B 256
#define T 1024
#define NSB 786   // score blocks = ceil(V/64)
#define WUP 2     // warmup steps (Delta*tau ~ 0.031/chunk; worst-case 4.0 << 466)
#define CL 8      // counted steps per chunk
#define NCH 128   // chunks per chain
#define NST (CL + WUP)

typedef _Float16 half8 __attribute__((ext_vector_type(8)));
typedef float f32x4 __attribute__((ext_vector_type(4)));
typedef __fp16 fp16x2 __attribute__((ext_vector_type(2)));

__device__ __forceinline__ unsigned pkh2(float x, float y) {
  fp16x2 v = __builtin_amdgcn_cvt_pkrtz(x, y);
  return __builtin_bit_cast(unsigned, v);
}
__device__ __forceinline__ unsigned short f16b(float x) {
  fp16x2 v = __builtin_amdgcn_cvt_pkrtz(x, x);
  return (unsigned short)(__builtin_bit_cast(unsigned, v) & 0xFFFFu);
}

// DPP wave reduces (result valid in lane 63)
__device__ __forceinline__ float wave_max63(float x) {
  int xi;
#define MSTEP(ctrl, rm, bm)                                                          \
  xi = __builtin_amdgcn_update_dpp(__float_as_int(x), __float_as_int(x), ctrl, rm,   \
                                   bm, false);                                       \
  x = fmaxf(x, __int_as_float(xi));
  MSTEP(0x111, 0xf, 0xf)
  MSTEP(0x112, 0xf, 0xf)
  MSTEP(0x114, 0xf, 0xe)
  MSTEP(0x118, 0xf, 0xc)
  MSTEP(0x142, 0xa, 0xf)
  MSTEP(0x143, 0xc, 0xf)
#undef MSTEP
  return x;
}
__device__ __forceinline__ float wave_sum63(float x) {
  int xi;
#define SSTEP(ctrl, rm, bm)                                                          \
  xi = __builtin_amdgcn_update_dpp(0, __float_as_int(x), ctrl, rm, bm, true);        \
  x = x + __int_as_float(xi);
  SSTEP(0x111, 0xf, 0xf)
  SSTEP(0x112, 0xf, 0xf)
  SSTEP(0x114, 0xf, 0xe)
  SSTEP(0x118, 0xf, 0xc)
  SSTEP(0x142, 0xa, 0xf)
  SSTEP(0x143, 0xc, 0xf)
#undef SSTEP
  return x;
}

// fused prep: blocks 0..127 = transA row; block 128 = tagh + pi + zero(out)
__global__ void __launch_bounds__(128) k_prep(
    const float* __restrict__ trans_w, const float* __restrict__ trans_b,
    const float* __restrict__ trans_q, const float* __restrict__ tag_w,
    const float* __restrict__ initl, unsigned short* __restrict__ AbfH,
    uint4* __restrict__ Tbf, float* __restrict__ pivec, float* __restrict__ out) {
  __shared__ __align__(16) float qs[H];
  __shared__ float red[2];
  int bid = blockIdx.x;
  int j = threadIdx.x;
  if (bid < 128) {
    int i = bid;
    qs[j] = trans_q[j];
    __syncthreads();
    const float* wrow = trans_w + (size_t)(i * K + j) * H;
    float acc = 0.f;
#pragma unroll
    for (int h = 0; h < H; h += 4) {
      float4 w4 = *(const float4*)(wrow + h);
      float4 q4 = *(const float4*)(qs + h);
      acc += w4.x * q4.x + w4.y * q4.y + w4.z * q4.z + w4.w * q4.w;
    }
    float logit = acc + trans_b[i * K + j];
    int wid = j >> 6;
    float m = logit;
    for (int o = 32; o; o >>= 1) m = fmaxf(m, __shfl_xor(m, o, 64));
    if ((j & 63) == 0) red[wid] = m;
    __syncthreads();
    m = fmaxf(red[0], red[1]);
    __syncthreads();
    float e = __expf(logit - m);
    float s = e;
    for (int o = 32; o; o >>= 1) s += __shfl_xor(s, o, 64);
    if ((j & 63) == 0) red[wid] = s;
    __syncthreads();
    s = red[0] + red[1];
    float a = e / s;
    int kt = i >> 5;
    int g = (i & 31) >> 3;
    int lane = 16 * g + (j & 15);
    int n = j >> 4;
    int ee = i & 7;
    AbfH[(size_t)(((kt * 8 + n) * 64 + lane) * 8 + ee)] = f16b(a);
  } else {
    if (j == 0) out[0] = 0.f;
    // tagh: tag B-fragments
    for (int f = j; f < 2048; f += 128) {
      int lane = f & 63;
      int rest = f >> 6;
      int n = rest & 7, kt = rest >> 3;
      int k = 16 * n + (lane & 15);
      int d0 = 32 * kt + 8 * (lane >> 4);
      const float* src = tag_w + (size_t)k * K + d0;
      float4 a = *(const float4*)src;
      float4 c = *(const float4*)(src + 4);
      Tbf[f] = make_uint4(pkh2(a.x, a.y), pkh2(a.z, a.w), pkh2(c.x, c.y), pkh2(c.z, c.w));
    }
    // pi
    float v = initl[j];
    int wid = j >> 6;
    float m = v;
    for (int o = 32; o; o >>= 1) m = fmaxf(m, __shfl_xor(m, o, 64));
    if ((j & 63) == 0) red[wid] = m;
    __syncthreads();
    m = fmaxf(red[0], red[1]);
    __syncthreads();
    float e = __expf(v - m);
    float s = e;
    for (int o = 32; o; o >>= 1) s += __shfl_xor(s, o, 64);
    if ((j & 63) == 0) red[wid] = s;
    __syncthreads();
    s = red[0] + red[1];
    pivec[j] = e / s;
  }
}

// scoresH = tag.word^T + bias via MFMA, 64 words/block; + fused per-k lse partials
__global__ void __launch_bounds__(256) k_scores(const float* __restrict__ word_w,
                                                const float* __restrict__ word_b,
                                                const uint4* __restrict__ Tbf,
                                                _Float16* __restrict__ scoresH,
                                                float* __restrict__ pmaxP,
                                                float* __restrict__ psumP) {
  __shared__ __align__(16) uint4 TbfL[2048];        // 32 KB
  __shared__ __align__(16) _Float16 outT[64][136];  // 17.4 KB
  int tid = threadIdx.x;
  int wv = tid >> 6, l = tid & 63;
  int c = l & 15, g = l >> 4;
  int wbase = blockIdx.x * 64;
#pragma unroll
  for (int q = 0; q < 8; q++) TbfL[q * 256 + tid] = Tbf[q * 256 + tid];
  int wa = min(wbase + wv * 16 + c, V - 1);
  const float* wrow = word_w + (size_t)wa * K + 8 * g;
  uint4 A0, A1, A2, A3;
#define LDA(kt, dst)                                                        \
  {                                                                         \
    float4 x = *(const float4*)(wrow + 32 * kt);                            \
    float4 y = *(const float4*)(wrow + 32 * kt + 4);                        \
    dst = make_uint4(pkh2(x.x, x.y), pkh2(x.z, x.w), pkh2(y.x, y.y), pkh2(y.z, y.w)); \
  }
  LDA(0, A0) LDA(1, A1) LDA(2, A2) LDA(3, A3)
#undef LDA
  float wb[4];
#pragma unroll
  for (int r = 0; r < 4; r++) wb[r] = word_b[min(wbase + wv * 16 + 4 * g + r, V - 1)];
  __syncthreads();
  f32x4 acc[8];
#pragma unroll
  for (int n = 0; n < 8; n++) acc[n] = (f32x4){0.f, 0.f, 0.f, 0.f};
#define MK(kt, AV)                                                          \
  {                                                                         \
    half8 ao = __builtin_bit_cast(half8, AV);                               \
    _Pragma("unroll") for (int n = 0; n < 8; n++) {                         \
      half8 bo = __builtin_bit_cast(half8, TbfL[(kt * 8 + n) * 64 + l]);    \
      acc[n] = __builtin_amdgcn_mfma_f32_16x16x32_f16(ao, bo, acc[n], 0, 0, 0); \
    }                                                                       \
  }
  MK(0, A0) MK(1, A1) MK(2, A2) MK(3, A3)
#undef MK
#pragma unroll
  for (int n = 0; n < 8; n++) {
#pragma unroll
    for (int r = 0; r < 4; r++)
      outT[wv * 16 + 4 * g + r][16 * n + c] = (_Float16)(acc[n][r] + wb[r]);
  }
  __syncthreads();
#pragma unroll
  for (int q = 0; q < 4; q++) {
    int idx = q * 256 + tid;
    int wl = idx >> 4, part = idx & 15;
    int w = wbase + wl;
    if (w < V) {
      uint4 v = *(const uint4*)&outT[wl][part * 8];
      *(uint4*)&scoresH[(size_t)w * K + part * 8] = v;
    }
  }
  // fused per-k (max, sumexp) partials over this block's valid words
  int nw = min(64, V - wbase);
  int kk = tid & 127, hf = tid >> 7;
  float pm = -1e30f, psv = 0.f;
  for (int q = 0; q < 32; q++) {
    int wl = hf * 32 + q;
    if (wl < nw) {
      float v = (float)outT[wl][kk];
      if (v > pm) { psv *= __expf(pm - v); pm = v; }
      psv += __expf(v - pm);
    }
  }
  pmaxP[blockIdx.x * 256 + tid] = pm;
  psumP[blockIdx.x * 256 + tid] = psv;
}

// parallel lse: one block per state k; 256 threads reduce 786x2 partials
__global__ void __launch_bounds__(256) k_lsefin(const float* __restrict__ pmaxP,
                                                const float* __restrict__ psumP,
                                                float* __restrict__ lse) {
  __shared__ float sm[4], ss[4];
  int k = blockIdx.x;
  int tid = threadIdx.x;
  float m = -1e30f, s = 0.f;
  for (int e = tid; e < 2 * NSB; e += 256) {
    int blk = e >> 1, half = e & 1;
    float pm = pmaxP[blk * 256 + half * 128 + k];
    float pv = psumP[blk * 256 + half * 128 + k];
    float M = fmaxf(m, pm);
    s = s * __expf(m - M) + pv * __expf(pm - M);
    m = M;
  }
#pragma unroll
  for (int o = 32; o; o >>= 1) {
    float mo = __shfl_xor(m, o, 64);
    float so = __shfl_xor(s, o, 64);
    float M = fmaxf(m, mo);
    s = s * __expf(m - M) + so * __expf(mo - M);
    m = M;
  }
  int wv = tid >> 6;
  if ((tid & 63) == 0) { sm[wv] = m; ss[wv] = s; }
  __syncthreads();
  if (tid == 0) {
    float M = fmaxf(fmaxf(sm[0], sm[1]), fmaxf(sm[2], sm[3]));
    float st = ss[0] * __expf(sm[0] - M) + ss[1] * __expf(sm[1] - M) +
               ss[2] * __expf(sm[2] - M) + ss[3] * __expf(sm[3] - M);
    lse[k] = M + __logf(st);
  }
}

// chunk-parallel forward: 8 waves, 128 chunks of CL=8 counted steps (WUP=2 warmup);
// builtin MFMA (B from LDS), Qt-transposed LDS exchange; eb + row-max computed
// IN-REGISTER during prefetch (exp off critical path); atomic loss epilogue.
__global__ void __launch_bounds__(512, 1) k_forward(
    const int* __restrict__ emis, const _Float16* __restrict__ scoresH,
    const float* __restrict__ lse, const uint4* __restrict__ Abf_g,
    const float* __restrict__ pivec, float* __restrict__ out) {
  __shared__ __align__(16) uint4 AbfL[2048];  // 32 KB
  __shared__ float Qt[8][16 * 132];           // 67.6 KB, per-wave [m][j] w/ pad
  __shared__ int es[T];
  __shared__ float red[8];
  int b = blockIdx.x;
  int tid = threadIdx.x;
  int wv = tid >> 6, l = tid & 63;
  int c16 = l & 15, g = l >> 4;
  int chunk = 16 * wv + c16;   // 0..127
  for (int i = tid; i < T; i += 512) es[i] = emis[b * T + i];
  for (int p = tid; p < 2048; p += 512) AbfL[p] = Abf_g[p];
  int Jb[4];
#pragma unroll
  for (int kt = 0; kt < 4; kt++) Jb[kt] = 32 * kt + 8 * g;
  // per-lane lse registers
  f32x4 lseR[8];
#pragma unroll
  for (int kt = 0; kt < 4; kt++) {
    lseR[2 * kt] = *(const f32x4*)(lse + Jb[kt]);
    lseR[2 * kt + 1] = *(const f32x4*)(lse + Jb[kt] + 4);
  }
  float2 lse2 = *(const float2*)(lse + 2 * l);
  __syncthreads();

  // helper macro: from raw score fragments sb[4], produce eb[4] (f16 pairs) + mb
#define MAKE_EB(SB, EB, MB)                                                          \
  {                                                                                  \
    float xx[4][8];                                                                  \
    float mx = -1e30f;                                                               \
    _Pragma("unroll") for (int kt = 0; kt < 4; kt++) {                               \
      const _Float16* sh = (const _Float16*)&SB[kt];                                 \
      _Pragma("unroll") for (int i = 0; i < 4; i++) {                                \
        xx[kt][i] = (float)sh[i] - lseR[2 * kt][i];                                  \
        mx = fmaxf(mx, xx[kt][i]);                                                   \
      }                                                                              \
      _Pragma("unroll") for (int i = 0; i < 4; i++) {                                \
        xx[kt][4 + i] = (float)sh[4 + i] - lseR[2 * kt + 1][i];                      \
        mx = fmaxf(mx, xx[kt][4 + i]);                                               \
      }                                                                              \
    }                                                                                \
    mx = fmaxf(mx, __shfl_xor(mx, 16, 64));                                          \
    mx = fmaxf(mx, __shfl_xor(mx, 32, 64));                                          \
    _Pragma("unroll") for (int kt = 0; kt < 4; kt++) {                               \
      EB[kt] = make_uint4(                                                           \
          pkh2(__expf(xx[kt][0] - mx), __expf(xx[kt][1] - mx)),                      \
          pkh2(__expf(xx[kt][2] - mx), __expf(xx[kt][3] - mx)),                      \
          pkh2(__expf(xx[kt][4] - mx), __expf(xx[kt][5] - mx)),                      \
          pkh2(__expf(xx[kt][6] - mx), __expf(xx[kt][7] - mx)));                     \
    }                                                                                \
    MB = mx;                                                                         \
  }

  // exact alpha(t=0): mb0 = max over full row of (s - lse), via wave max
  int w0 = es[0];
  float2 sc2;
  {
    const _Float16* s0p = scoresH + (size_t)w0 * K + 2 * l;
    sc2.x = (float)s0p[0]; sc2.y = (float)s0p[1];
  }
  float ml0 = fmaxf(sc2.x - lse2.x, sc2.y - lse2.y);
  float am0 = wave_max63(ml0);
  float mb0 = __int_as_float(__builtin_amdgcn_readlane(__float_as_int(am0), 63));
  float a0v = pivec[2 * l] * __expf(sc2.x - lse2.x - mb0);
  float a1v = pivec[2 * l + 1] * __expf(sc2.y - lse2.y - mb0);
  float am = wave_max63(fmaxf(a0v, a1v));
  float mu1 = __int_as_float(__builtin_amdgcn_readlane(__float_as_int(am), 63));
  mu1 = fmaxf(mu1, 1e-30f);
  float lmu1 = __logf(mu1);
  uint4 P0[4];
  {
    float inv = 1.0f / mu1;
    const uint4* s0v = (const uint4*)(scoresH + (size_t)w0 * K);
#pragma unroll
    for (int kt = 0; kt < 4; kt++) {
      uint4 su = s0v[4 * kt + g];
      const _Float16* sh = (const _Float16*)&su;
      float v[8];
#pragma unroll
      for (int i = 0; i < 4; i++)
        v[i] = pivec[Jb[kt] + i] * __expf((float)sh[i] - lseR[2 * kt][i] - mb0) * inv;
#pragma unroll
      for (int i = 0; i < 4; i++)
        v[4 + i] = pivec[Jb[kt] + 4 + i] * __expf((float)sh[4 + i] - lseR[2 * kt + 1][i] - mb0) * inv;
      P0[kt] = make_uint4(pkh2(v[0], v[1]), pkh2(v[2], v[3]), pkh2(v[4], v[5]), pkh2(v[6], v[7]));
    }
  }
  uint4 Pk[4];
  unsigned one2 = 0x3C003C00u;
  Pk[0] = Pk[1] = Pk[2] = Pk[3] = make_uint4(one2, one2, one2, one2);
  float zprev = 1.0f, lzS = 0.f, lzE = 0.f, logS = 0.f, Cacc = 0.f;
  int cend = (chunk == NCH - 1) ? (WUP + CL - 2) : (WUP + CL - 1);
  float* Qw = Qt[wv];
  // prefetch step 0's token: eb + mb in-register
  int t0 = max(CL * chunk - (WUP - 1), 0);
  int tok0 = es[t0];
  float mbC;
  uint4 ebC[4];
  {
    const uint4* sp = (const uint4*)(scoresH + (size_t)tok0 * K);
    uint4 sb[4];
#pragma unroll
    for (int kt = 0; kt < 4; kt++) sb[kt] = sp[4 * kt + g];
    MAKE_EB(sb, ebC, mbC)
  }
  for (int s = 0; s < NST; s++) {
    // prefetch step s+1's token (eb/mb computed off critical path)
    int tn = CL * chunk + (s + 1) - (WUP - 1);
    tn = max(tn, 0); tn = min(tn, T - 1);
    int tokN = es[tn];
    const uint4* spN = (const uint4*)(scoresH + (size_t)tokN * K);
    uint4 sbN[4];
#pragma unroll
    for (int kt = 0; kt < 4; kt++) sbN[kt] = spN[4 * kt + g];
    float mbN;
    uint4 ebN[4];
    MAKE_EB(sbN, ebN, mbN)
    // 32 mfma: acc[n] = sum_kt P[kt] * Abf[kt][n]
    f32x4 acc[8];
#pragma unroll
    for (int n = 0; n < 8; n++) acc[n] = (f32x4){0.f, 0.f, 0.f, 0.f};
#pragma unroll
    for (int kt = 0; kt < 4; kt++) {
      half8 ao = __builtin_bit_cast(half8, Pk[kt]);
#pragma unroll
      for (int n = 0; n < 8; n++) {
        half8 bo = __builtin_bit_cast(half8, AbfL[(kt * 8 + n) * 64 + l]);
        acc[n] = __builtin_amdgcn_mfma_f32_16x16x32_f16(ao, bo, acc[n], 0, 0, 0);
      }
    }
    // scatter D to Qt[m=4g+r][j=16n+c16]  (2-way banks: free)
#pragma unroll
    for (int n = 0; n < 8; n++) {
#pragma unroll
      for (int r = 0; r < 4; r++) Qw[(4 * g + r) * 132 + 16 * n + c16] = acc[n][r];
    }
    asm volatile("s_waitcnt lgkmcnt(0)" ::: "memory");
    __builtin_amdgcn_sched_barrier(0);
    // gather own chunk (row m=c16): p = q * eb * rr
    float rr = __builtin_amdgcn_rcpf(fmaxf(zprev, 1e-30f));
    float lzp = __logf(fmaxf(zprev, 1e-30f));
    float pmax = 0.f, lsum = 0.f;
    uint4 newP[4];
#pragma unroll
    for (int kt = 0; kt < 4; kt++) {
      f32x4 q0 = *(const f32x4*)&Qw[c16 * 132 + Jb[kt]];
      f32x4 q1 = *(const f32x4*)&Qw[c16 * 132 + Jb[kt] + 4];
      const _Float16* ebh = (const _Float16*)&ebC[kt];
      float pv[8];
#pragma unroll
      for (int i = 0; i < 4; i++) {
        float p = q0[i] * (float)ebh[i] * rr;
        pv[i] = p; pmax = fmaxf(pmax, p); lsum += p;
      }
#pragma unroll
      for (int i = 0; i < 4; i++) {
        float p = q1[i] * (float)ebh[4 + i] * rr;
        pv[4 + i] = p; pmax = fmaxf(pmax, p); lsum += p;
      }
      newP[kt] = make_uint4(pkh2(pv[0], pv[1]), pkh2(pv[2], pv[3]),
                            pkh2(pv[4], pv[5]), pkh2(pv[6], pv[7]));
    }
    pmax = fmaxf(pmax, __shfl_xor(pmax, 16, 64));
    pmax = fmaxf(pmax, __shfl_xor(pmax, 32, 64));
    float znew = pmax;
    if (s == WUP - 1) {
      if (chunk == 0) {
#pragma unroll
        for (int kt = 0; kt < 4; kt++) newP[kt] = P0[kt];
        znew = 1.0f;
      }
      lzS = __logf(fmaxf(znew, 1e-30f));
    }
    bool counted = (s >= WUP) && (s <= cend);
    if (counted) Cacc += lzp + mbC;
    if (s == WUP + CL - 2) {
      float ssum = lsum + __shfl_xor(lsum, 16, 64);
      ssum += __shfl_xor(ssum, 32, 64);
      logS = __logf(fmaxf(ssum, 1e-30f));
    }
    if (s == WUP + CL - 1) lzE = __logf(fmaxf(znew, 1e-30f));
#pragma unroll
    for (int kt = 0; kt < 4; kt++) Pk[kt] = newP[kt];
    zprev = znew;
#pragma unroll
    for (int kt = 0; kt < 4; kt++) ebC[kt] = ebN[kt];
    mbC = mbN;
  }
#undef MAKE_EB
  // epilogue: per-chunk R -> block sum -> atomic loss
  float Rv = Cacc - lzS;
  Rv += (chunk == NCH - 1) ? logS : lzE;
  if (chunk == 0) Rv += mb0 + lmu1;
  float val = (l < 16) ? Rv : 0.f;
  float ws = wave_sum63(val);
  if (l == 63) red[wv] = ws;
  __syncthreads();
  if (tid == 0) {
    float tot = red[0] + red[1] + red[2] + red[3] + red[4] + red[5] + red[6] + red[7];
    atomicAdd(out, -tot * (1.0f / (float)B));
  }
}

extern "C" void kernel_launch(void* const* d_in, const int* in_sizes, int n_in,
                              void* d_out, int out_size, void* d_ws, size_t ws_size,
                              hipStream_t stream) {
  const int*   emis   = (const int*)d_in[0];
  const float* initl  = (const float*)d_in[1];
  const float* tagw   = (const float*)d_in[2];
  const float* wordw  = (const float*)d_in[3];
  const float* wordb  = (const float*)d_in[4];
  const float* transw = (const float*)d_in[5];
  const float* transb = (const float*)d_in[6];
  const float* transq = (const float*)d_in[7];
  float* ws = (float*)d_ws;
  size_t off = 0;
  _Float16* scoresH = (_Float16*)(ws + off); off += (size_t)V * K / 2;
  uint4* Abf_g      = (uint4*)(ws + off);    off += 8192;
  uint4* Tbf_g      = (uint4*)(ws + off);    off += 8192;
  float* pivec      = ws + off; off += K;
  float* lse        = ws + off; off += K;
  float* pmaxP      = ws + off; off += (size_t)NSB * 256;
  float* psumP      = ws + off; off += (size_t)NSB * 256;
  float* out = (float*)d_out;

  hipLaunchKernelGGL(k_prep, dim3(129), dim3(128), 0, stream,
                     transw, transb, transq, tagw, initl,
                     (unsigned short*)Abf_g, Tbf_g, pivec, out);
  hipLaunchKernelGGL(k_scores, dim3(NSB), dim3(256), 0, stream,
                     wordw, wordb, Tbf_g, scoresH, pmaxP, psumP);
  hipLaunchKernelGGL(k_lsefin, dim3(K), dim3(256), 0, stream, pmaxP, psumP, lse);
  hipLaunchKernelGGL(k_forward, dim3(B), dim3(512), 0, stream, emis, scoresH, lse, Abf_g, pivec, out);
}